// Round 1
// baseline (2138.037 us; speedup 1.0000x reference)
//
#include <hip/hip_runtime.h>
#include <math.h>

// Problem constants
#define Nn 50000
#define Ee 800000
#define Bb 256
#define Hh 64
#define TPB 256
#define CHUNK 512

// ---------------- embed: h = x @ W(4x64) + b ----------------
__global__ void k_embed(const float* __restrict__ x, const float* __restrict__ W,
                        const float* __restrict__ b, float* __restrict__ h) {
    int idx = blockIdx.x * blockDim.x + threadIdx.x;
    if (idx >= Nn * Hh) return;
    int n = idx >> 6, j = idx & 63;
    float acc = b[j];
#pragma unroll
    for (int d = 0; d < 4; ++d) acc += x[n * 4 + d] * W[d * Hh + j];
    h[idx] = acc;
}

// ---------------- CSR build ----------------
__global__ void k_hist(const int* __restrict__ dst, int* __restrict__ counts) {
    int e = blockIdx.x * blockDim.x + threadIdx.x;
    if (e < Ee) atomicAdd(&counts[dst[e]], 1);
}

__global__ void k_scan1(const int* __restrict__ counts, int* __restrict__ off,
                        int* __restrict__ chunksum) {
    __shared__ int s[CHUNK];
    int t = threadIdx.x;
    int base = blockIdx.x * CHUNK;
    int v = (base + t < Nn) ? counts[base + t] : 0;
    s[t] = v;
    __syncthreads();
    for (int d = 1; d < CHUNK; d <<= 1) {
        int u = (t >= d) ? s[t - d] : 0;
        __syncthreads();
        s[t] += u;
        __syncthreads();
    }
    if (base + t < Nn) off[base + t + 1] = s[t];
    if (t == CHUNK - 1) chunksum[blockIdx.x] = s[t];
}

__global__ void k_scan2(int* __restrict__ chunksum, int nch) {
    if (blockIdx.x == 0 && threadIdx.x == 0) {
        int run = 0;
        for (int i = 0; i < nch; ++i) { int v = chunksum[i]; chunksum[i] = run; run += v; }
    }
}

__global__ void k_scan3(int* __restrict__ off, const int* __restrict__ chunkoff) {
    int i = blockIdx.x * blockDim.x + threadIdx.x;
    if (i > Nn) return;
    if (i == 0) { off[0] = 0; return; }
    off[i] += chunkoff[(i - 1) >> 9];  // CHUNK=512
}

__global__ void k_copy(const int* __restrict__ off, int* __restrict__ cursor) {
    int n = blockIdx.x * blockDim.x + threadIdx.x;
    if (n < Nn) cursor[n] = off[n];
}

__global__ void k_scatter(const int* __restrict__ src, const int* __restrict__ dst,
                          const float* __restrict__ ea, int* __restrict__ cursor,
                          int* __restrict__ csrc, int* __restrict__ cdst,
                          float* __restrict__ cea) {
    int e = blockIdx.x * blockDim.x + threadIdx.x;
    if (e >= Ee) return;
    int d = dst[e];
    int p = atomicAdd(&cursor[d], 1);
    csrc[p] = src[e];
    cdst[p] = d;
    cea[p] = ea[e];
}

// ---------------- conv linear: xl = h@Wl+bl, xr = h@Wr+br ----------------
__global__ void k_lin(const float* __restrict__ h, const float* __restrict__ Wl,
                      const float* __restrict__ bl, const float* __restrict__ Wr,
                      const float* __restrict__ br, float* __restrict__ xl,
                      float* __restrict__ xr) {
    int idx = blockIdx.x * blockDim.x + threadIdx.x;
    if (idx >= Nn * Hh) return;
    int n = idx >> 6, j = idx & 63;
    float al = bl[j], ar = br[j];
    const float* hr = h + n * Hh;
#pragma unroll 8
    for (int i = 0; i < Hh; ++i) {
        float hv = hr[i];
        al += hv * Wl[i * Hh + j];
        ar += hv * Wr[i * Hh + j];
    }
    xl[idx] = al;
    xr[idx] = ar;
}

// ---------------- edge scores: wave per CSR slot ----------------
__global__ void k_edge(const float* __restrict__ xl, const float* __restrict__ xr,
                       const float* __restrict__ cea, const int* __restrict__ csrc,
                       const int* __restrict__ cdst, const float* __restrict__ We,
                       const float* __restrict__ att, float* __restrict__ ecsr) {
    int gid = blockIdx.x * blockDim.x + threadIdx.x;
    int p = gid >> 6, j = gid & 63;
    if (p >= Ee) return;
    int s = csrc[p], d = cdst[p];
    float m = xl[s * Hh + j] + xr[d * Hh + j] + cea[p] * We[j];
    m = m > 0.f ? m : 0.2f * m;
    float v = m * att[j];
#pragma unroll
    for (int o = 32; o > 0; o >>= 1) v += __shfl_xor(v, o);
    if (j == 0) ecsr[p] = v;
}

// ---------------- per-node softmax over incoming edges (in-place -> alpha) ----------------
__global__ void k_softmax(const int* __restrict__ off, float* __restrict__ ecsr) {
    int n = blockIdx.x * blockDim.x + threadIdx.x;
    if (n >= Nn) return;
    int s = off[n], t = off[n + 1];
    if (t <= s) return;
    float mx = -1e30f;
    for (int p = s; p < t; ++p) mx = fmaxf(mx, ecsr[p]);
    float sum = 0.f;
    for (int p = s; p < t; ++p) {
        float v = expf(ecsr[p] - mx);
        ecsr[p] = v;
        sum += v;
    }
    float inv = 1.f / sum;
    for (int p = s; p < t; ++p) ecsr[p] *= inv;
}

// ---------------- aggregate + bias + SiLU: wave per node ----------------
__global__ void k_agg(const float* __restrict__ xl, const float* __restrict__ ecsr,
                      const int* __restrict__ csrc, const int* __restrict__ off,
                      const float* __restrict__ bias, float* __restrict__ hout) {
    int gid = blockIdx.x * blockDim.x + threadIdx.x;
    int n = gid >> 6, j = gid & 63;
    if (n >= Nn) return;
    float acc = 0.f;
    int s = off[n], t = off[n + 1];
    for (int p = s; p < t; ++p) acc += ecsr[p] * xl[csrc[p] * Hh + j];
    float o = acc + bias[j];
    hout[n * Hh + j] = o / (1.f + expf(-o));  // silu
}

// ---------------- W1 transpose (64x128 -> 128x64) ----------------
__global__ void k_w1t(const float* __restrict__ W1, float* __restrict__ W1T) {
    int idx = blockIdx.x * blockDim.x + threadIdx.x;
    if (idx >= 2 * Hh * Hh) return;
    int k = idx >> 6, i = idx & 63;
    W1T[k * Hh + i] = W1[i * 2 * Hh + k];
}

// ---------------- RK4 eval: thread per node, f(y)=tanh(y@W1+b1)@W2+b2 ----------------
template <int STAGE>
__global__ void k_ode(float* __restrict__ h, const float* __restrict__ kprev,
                      const float* __restrict__ W1T, const float* __restrict__ b1,
                      const float* __restrict__ W2, const float* __restrict__ b2,
                      float* __restrict__ kout, float* __restrict__ ksum) {
    int n = blockIdx.x * blockDim.x + threadIdx.x;
    if (n >= Nn) return;
    const float cf = (STAGE == 3) ? 1.0f : 0.5f;
    float y[Hh];
#pragma unroll
    for (int i = 0; i < Hh; ++i) {
        float hv = h[n * Hh + i];
        y[i] = (STAGE == 0) ? hv : hv + cf * kprev[n * Hh + i];
    }
    float outv[Hh];
#pragma unroll
    for (int j = 0; j < Hh; ++j) outv[j] = b2[j];
    for (int k = 0; k < 2 * Hh; ++k) {
        float z = b1[k];
#pragma unroll
        for (int i = 0; i < Hh; ++i) z += y[i] * W1T[k * Hh + i];
        float t = tanhf(z);
#pragma unroll
        for (int j = 0; j < Hh; ++j) outv[j] += t * W2[k * Hh + j];
    }
#pragma unroll
    for (int j = 0; j < Hh; ++j) {
        if (STAGE == 0) {
            kout[n * Hh + j] = outv[j];
            ksum[n * Hh + j] = outv[j];
        } else if (STAGE == 3) {
            h[n * Hh + j] = h[n * Hh + j] + (ksum[n * Hh + j] + outv[j]) * (1.f / 6.f);
        } else {
            kout[n * Hh + j] = outv[j];
            ksum[n * Hh + j] += 2.f * outv[j];
        }
    }
}

// ---------------- pooling ----------------
__global__ void k_binit(int* __restrict__ gs, int* __restrict__ ge) {
    int b = threadIdx.x;
    if (b < Bb) { gs[b] = 0; ge[b] = 0; }
}

__global__ void k_bounds(const int* __restrict__ batch, int* __restrict__ gs,
                         int* __restrict__ ge) {
    int n = blockIdx.x * blockDim.x + threadIdx.x;
    if (n >= Nn) return;
    int b = batch[n];
    if (n == 0 || batch[n - 1] != b) gs[b] = n;
    if (n == Nn - 1 || batch[n + 1] != b) ge[b] = n + 1;
}

__global__ void k_pool(const float* __restrict__ h, const int* __restrict__ gs,
                       const int* __restrict__ ge, float* __restrict__ g) {
    int gid = blockIdx.x * blockDim.x + threadIdx.x;
    int b = gid >> 6, j = gid & 63;
    if (b >= Bb) return;
    int s = gs[b], e = ge[b];
    float sum = 0.f, mx = -1e30f;
    for (int n = s; n < e; ++n) {
        float v = h[n * Hh + j];
        sum += v;
        mx = fmaxf(mx, v);
    }
    int cnt = e - s;
    float mean = (cnt > 0) ? sum / (float)cnt : 0.f;
    float mxo = (cnt > 0) ? mx : 0.f;
    g[b * 2 * Hh + j] = mean;
    g[b * 2 * Hh + Hh + j] = mxo;
}

// ---------------- predictor head ----------------
__global__ void k_pred(const float* __restrict__ g, const float* __restrict__ W1,
                       const float* __restrict__ b1, const float* __restrict__ W2,
                       const float* __restrict__ b2, float* __restrict__ out) {
    int b = threadIdx.x;
    if (b >= Bb) return;
    const float* gr = g + b * 2 * Hh;
    float o = 0.f;
#pragma unroll 4
    for (int hh = 0; hh < 32; ++hh) {
        float a = b1[hh];
        for (int i = 0; i < 2 * Hh; ++i) a += gr[i] * W1[i * 32 + hh];
        float sl = a / (1.f + expf(-a));
        o += sl * W2[hh];
    }
    out[b] = o + b2[0];
}

extern "C" void kernel_launch(void* const* d_in, const int* in_sizes, int n_in,
                              void* d_out, int out_size, void* d_ws, size_t ws_size,
                              hipStream_t stream) {
    const float* x     = (const float*)d_in[0];
    const int*   ei    = (const int*)d_in[1];
    const float* ea    = (const float*)d_in[2];
    const int*   batch = (const int*)d_in[3];
    const float* embW  = (const float*)d_in[4];
    const float* embB  = (const float*)d_in[5];
    const float* c1Wl = (const float*)d_in[6];  const float* c1bl = (const float*)d_in[7];
    const float* c1Wr = (const float*)d_in[8];  const float* c1br = (const float*)d_in[9];
    const float* c1We = (const float*)d_in[10]; const float* c1att = (const float*)d_in[11];
    const float* c1bias = (const float*)d_in[12];
    const float* c2Wl = (const float*)d_in[13]; const float* c2bl = (const float*)d_in[14];
    const float* c2Wr = (const float*)d_in[15]; const float* c2br = (const float*)d_in[16];
    const float* c2We = (const float*)d_in[17]; const float* c2att = (const float*)d_in[18];
    const float* c2bias = (const float*)d_in[19];
    const float* oW1 = (const float*)d_in[20]; const float* ob1 = (const float*)d_in[21];
    const float* oW2 = (const float*)d_in[22]; const float* ob2 = (const float*)d_in[23];
    const float* pW1 = (const float*)d_in[24]; const float* pb1 = (const float*)d_in[25];
    const float* pW2 = (const float*)d_in[26]; const float* pb2 = (const float*)d_in[27];
    float* out = (float*)d_out;

    // workspace layout
    float* fws = (float*)d_ws;
    size_t o = 0;
    float* h    = fws + o; o += (size_t)Nn * Hh;
    float* xl   = fws + o; o += (size_t)Nn * Hh;
    float* xr   = fws + o; o += (size_t)Nn * Hh;
    float* ksum = fws + o; o += (size_t)Nn * Hh;
    float* ecsr = fws + o; o += Ee;
    float* cea  = fws + o; o += Ee;
    float* g    = fws + o; o += Bb * 2 * Hh;
    float* W1T  = fws + o; o += 2 * Hh * Hh;
    int* iws = (int*)(fws + o);
    size_t io = 0;
    int* counts = iws + io; io += Nn;
    int* off    = iws + io; io += Nn + 1;
    int* cursor = iws + io; io += Nn;
    int* chk    = iws + io; io += 128;
    int* gs     = iws + io; io += Bb;
    int* ge     = iws + io; io += Bb;
    int* csrc   = iws + io; io += Ee;
    int* cdst   = iws + io; io += Ee;

    const int* src = ei;
    const int* dst = ei + Ee;

    hipMemsetAsync(counts, 0, Nn * sizeof(int), stream);
    k_embed<<<(Nn * Hh + TPB - 1) / TPB, TPB, 0, stream>>>(x, embW, embB, h);
    k_hist<<<(Ee + TPB - 1) / TPB, TPB, 0, stream>>>(dst, counts);
    k_scan1<<<(Nn + CHUNK - 1) / CHUNK, CHUNK, 0, stream>>>(counts, off, chk);
    k_scan2<<<1, 64, 0, stream>>>(chk, (Nn + CHUNK - 1) / CHUNK);
    k_scan3<<<(Nn + 1 + TPB - 1) / TPB, TPB, 0, stream>>>(off, chk);
    k_copy<<<(Nn + TPB - 1) / TPB, TPB, 0, stream>>>(off, cursor);
    k_scatter<<<(Ee + TPB - 1) / TPB, TPB, 0, stream>>>(src, dst, ea, cursor, csrc, cdst, cea);

    // conv1
    k_lin<<<(Nn * Hh + TPB - 1) / TPB, TPB, 0, stream>>>(h, c1Wl, c1bl, c1Wr, c1br, xl, xr);
    k_edge<<<(Ee * 64 + TPB - 1) / TPB, TPB, 0, stream>>>(xl, xr, cea, csrc, cdst, c1We, c1att, ecsr);
    k_softmax<<<(Nn + TPB - 1) / TPB, TPB, 0, stream>>>(off, ecsr);
    k_agg<<<(Nn * Hh + TPB - 1) / TPB, TPB, 0, stream>>>(xl, ecsr, csrc, off, c1bias, h);

    // conv2
    k_lin<<<(Nn * Hh + TPB - 1) / TPB, TPB, 0, stream>>>(h, c2Wl, c2bl, c2Wr, c2br, xl, xr);
    k_edge<<<(Ee * 64 + TPB - 1) / TPB, TPB, 0, stream>>>(xl, xr, cea, csrc, cdst, c2We, c2att, ecsr);
    k_softmax<<<(Nn + TPB - 1) / TPB, TPB, 0, stream>>>(off, ecsr);
    k_agg<<<(Nn * Hh + TPB - 1) / TPB, TPB, 0, stream>>>(xl, ecsr, csrc, off, c2bias, h);

    // RK4 (kA = xl, kB = xr reuse)
    k_w1t<<<(2 * Hh * Hh + TPB - 1) / TPB, TPB, 0, stream>>>(oW1, W1T);
    k_ode<0><<<(Nn + TPB - 1) / TPB, TPB, 0, stream>>>(h, nullptr, W1T, ob1, oW2, ob2, xl, ksum);
    k_ode<1><<<(Nn + TPB - 1) / TPB, TPB, 0, stream>>>(h, xl, W1T, ob1, oW2, ob2, xr, ksum);
    k_ode<2><<<(Nn + TPB - 1) / TPB, TPB, 0, stream>>>(h, xr, W1T, ob1, oW2, ob2, xl, ksum);
    k_ode<3><<<(Nn + TPB - 1) / TPB, TPB, 0, stream>>>(h, xl, W1T, ob1, oW2, ob2, nullptr, ksum);

    // pooling + head
    k_binit<<<1, Bb, 0, stream>>>(gs, ge);
    k_bounds<<<(Nn + TPB - 1) / TPB, TPB, 0, stream>>>(batch, gs, ge);
    k_pool<<<(Bb * 64 + TPB - 1) / TPB, TPB, 0, stream>>>(h, gs, ge, g);
    k_pred<<<1, Bb, 0, stream>>>(g, pW1, pb1, pW2, pb2, out);
}